// Round 5
// baseline (457.691 us; speedup 1.0000x reference)
//
#include <hip/hip_runtime.h>
#include <hip/hip_bf16.h>
#include <stdint.h>

typedef __hip_bfloat16 bf16;
typedef __attribute__((ext_vector_type(8))) short v8s;   // 8 bf16 in 4 VGPRs
typedef __attribute__((ext_vector_type(4))) float v4f;   // MFMA C/D frag

__device__ __forceinline__ bf16 tob(float x) { return __float2bfloat16(x); }

// async global->LDS, 16B/lane. Canonical pattern ONLY: src = row_base + l*16,
// dst = lds_row_base + l*16 (correct under the verified wave-uniform-base model).
__device__ __forceinline__ void gload16(const void* g, void* l) {
  __builtin_amdgcn_global_load_lds(
      (const __attribute__((address_space(1))) uint32_t*)g,
      (__attribute__((address_space(3))) uint32_t*)l, 16, 0, 0);
}

// sum over the 16 lanes of a DPP row (VALU pipe only); verified in R4 epilogue
__device__ __forceinline__ float rsum16(float v) {
  union { float f; int i; } u, w;
  u.f = v;
  w.i = __builtin_amdgcn_update_dpp(u.i, u.i, 0x121, 0xf, 0xf, false); u.f += w.f;
  w.i = __builtin_amdgcn_update_dpp(u.i, u.i, 0x122, 0xf, 0xf, false); u.f += w.f;
  w.i = __builtin_amdgcn_update_dpp(u.i, u.i, 0x124, 0xf, 0xf, false); u.f += w.f;
  w.i = __builtin_amdgcn_update_dpp(u.i, u.i, 0x128, 0xf, 0xf, false); u.f += w.f;
  return u.f;
}

// ============ merged prep: [0,512) lin1, [512,768) gp, [768,1024) w2t ============
__global__ void k_prep(const float* __restrict__ fea, const float* __restrict__ Wl1,
                       const float* __restrict__ bl1, const float* __restrict__ Wc1,
                       const float* __restrict__ bc1, const float* __restrict__ Wc2,
                       float* __restrict__ h1, float* __restrict__ gp,
                       bf16* __restrict__ W2T) {
  const int blk = blockIdx.x;
  if (blk < 768) {                       // lin1 or gp: 16 outputs x 16 k-slices
    __shared__ float red[256];
    const int nl = threadIdx.x & 15, ks = threadIdx.x >> 4;
    const bool isl1 = blk < 512;
    const int o = (isl1 ? blk : blk - 512) * 16 + nl;
    const int b = isl1 ? (o >> 10) : (o >> 9);
    const int n = isl1 ? (o & 1023) : (o & 511);
    const int LD = isl1 ? 1024 : 512;
    const float* fr = fea + (b << 10) + ks * 64;
    const float* wp = (isl1 ? Wl1 : (Wc1 + (size_t)5 * 512)) + (size_t)(ks * 64) * LD + n;
    float a0 = 0.f, a1 = 0.f, a2 = 0.f, a3 = 0.f;
#pragma unroll 4
    for (int j = 0; j < 64; j += 4) {
      a0 = fmaf(fr[j + 0], wp[(size_t)(j + 0) * LD], a0);
      a1 = fmaf(fr[j + 1], wp[(size_t)(j + 1) * LD], a1);
      a2 = fmaf(fr[j + 2], wp[(size_t)(j + 2) * LD], a2);
      a3 = fmaf(fr[j + 3], wp[(size_t)(j + 3) * LD], a3);
    }
    red[threadIdx.x] = (a0 + a1) + (a2 + a3);
    __syncthreads();
    if (threadIdx.x < 16) {
      float s = isl1 ? bl1[n] : bc1[n];
#pragma unroll
      for (int i = 0; i < 16; ++i) s += red[i * 16 + threadIdx.x];
      if (isl1) h1[o] = fmaxf(s, 0.f); else gp[o] = s;
    }
  } else {                               // W2T[n,k] = bf16(Wc2[k,n])
    __shared__ float tile[32][33];
    const int id = blk - 768;
    const int bx = id & 15, by = id >> 4;
    const int c = threadIdx.x & 31, r8 = threadIdx.x >> 5;
#pragma unroll
    for (int i = 0; i < 4; ++i) {
      int r = r8 + i * 8;
      tile[r][c] = Wc2[(by * 32 + r) * 512 + bx * 32 + c];
    }
    __syncthreads();
#pragma unroll
    for (int i = 0; i < 4; ++i) {
      int r = r8 + i * 8;
      W2T[(size_t)(bx * 32 + r) * 512 + by * 32 + c] = tob(tile[c][r]);
    }
  }
}

// ============ x = h1 @ W_l2 + b_l2; writes xout and seeds fine = x + bc3 ============
__global__ void k_lin2(const float* __restrict__ h1, const float* __restrict__ W,
                       const float* __restrict__ bias, const float* __restrict__ bc3,
                       float* __restrict__ xf, float* __restrict__ xout,
                       float* __restrict__ fine) {
  __shared__ float red[256];
  const int nl = threadIdx.x & 15, ks = threadIdx.x >> 4;
  const int o = blockIdx.x * 16 + nl;            // 0..24575
  const int b = o / 3072, n = o - b * 3072;
  const float* hr = h1 + (b << 10) + ks * 64;
  const float* wp = W + (size_t)(ks * 64) * 3072 + n;
  float a0 = 0.f, a1 = 0.f, a2 = 0.f, a3 = 0.f;
#pragma unroll 4
  for (int j = 0; j < 64; j += 4) {
    a0 = fmaf(hr[j + 0], wp[(size_t)(j + 0) * 3072], a0);
    a1 = fmaf(hr[j + 1], wp[(size_t)(j + 1) * 3072], a1);
    a2 = fmaf(hr[j + 2], wp[(size_t)(j + 2) * 3072], a2);
    a3 = fmaf(hr[j + 3], wp[(size_t)(j + 3) * 3072], a3);
  }
  red[threadIdx.x] = (a0 + a1) + (a2 + a3);
  __syncthreads();
  if (threadIdx.x < 16) {
    float s = bias[n];
#pragma unroll
    for (int i = 0; i < 16; ++i) s += red[i * 16 + threadIdx.x];
    xf[o] = s;
    xout[o] = s;
    const int c = n / 3, j = n - c * 3;
    const float seed = s + bc3[j];
    float* fp = fine + ((size_t)b * 16384 + c * 16) * 3 + j;
#pragma unroll
    for (int g = 0; g < 16; ++g) fp[g * 3] = seed;
  }
}

// ============ R[m,k] = bf16(relu(gp + grid·W01 + x·W234))  (131072,512) ============
__global__ void k_R(const float* __restrict__ gp, const float* __restrict__ xf,
                    const float* __restrict__ Wc1, bf16* __restrict__ R) {
  const int idx = blockIdx.x * 256 + threadIdx.x;  // 8388608 threads, 8 k each
  const int m = idx >> 6;
  const int kb = (idx & 63) << 3;
  const int b = m >> 14, f = m & 16383, c = f >> 4, g = f & 15;
  const float gx = -0.05f + (float)(g & 3) * (0.1f / 3.0f);
  const float gy = -0.05f + (float)(g >> 2) * (0.1f / 3.0f);
  const float* xp = xf + (b * 1024 + c) * 3;
  const float x0 = xp[0], x1 = xp[1], x2 = xp[2];
  const float* gpr = gp + (b << 9) + kb;
  const float* w0 = Wc1 + 0 * 512 + kb;
  const float* w1 = Wc1 + 1 * 512 + kb;
  const float* w2 = Wc1 + 2 * 512 + kb;
  const float* w3 = Wc1 + 3 * 512 + kb;
  const float* w4 = Wc1 + 4 * 512 + kb;
  union { bf16 h[8]; uint4 u; } out;
#pragma unroll
  for (int i = 0; i < 8; ++i) {
    float v = gpr[i];
    v = fmaf(gx, w0[i], v);
    v = fmaf(gy, w1[i], v);
    v = fmaf(x0, w2[i], v);
    v = fmaf(x1, w3[i], v);
    v = fmaf(x2, w4[i], v);
    out.h[i] = tob(fmaxf(v, 0.f));
  }
  *(uint4*)(R + (size_t)m * 512 + kb) = out.u;
}

// ============ barrier-free GEMM: R(global->reg) x W2T(LDS, full K) ============
// 256 blocks x 512 thr. Block = 2048 rows (Mgrp=blk&63) x 128 cols (blk>>6).
// Bs holds the whole B chunk (128 x 512 bf16, rows padded to 1040 B) -> exactly
// one __syncthreads in the kernel. A-frags stream from R with 1-kt prefetch.
// Same-Mgrp N-chunk blocks are 64 apart = same XCD -> A slice L2-local.
__global__ __launch_bounds__(512, 2)
void k_gemm(const bf16* __restrict__ R, const bf16* __restrict__ W2T,
            const float* __restrict__ bc2, const float* __restrict__ Wc3,
            float* __restrict__ fine) {
  __shared__ __align__(16) bf16 Bs[128 * 520];     // 133120 B -> 1 block/CU
  const int t = threadIdx.x;
  const int w = t >> 6, l = t & 63, q = l >> 4, lm = l & 15;
  const int wr = (w >> 1) * 64;                    // wave row base: 0/64/128/192
  const int wc = (w & 1) * 64;                     // wave col base: 0/64
  const int Mgrp = blockIdx.x & 63;
  const int Nbase = (blockIdx.x >> 6) * 128;

  // stage Bs once: wave w stages rows [w*16, w*16+16), canonical lane*16 pattern
  {
    const char* src = (const char*)W2T + (size_t)(Nbase + w * 16) * 1024 + l * 16;
    char* dst = (char*)Bs + (w * 16) * 1040 + l * 16;
#pragma unroll
    for (int r = 0; r < 16; ++r)
      gload16(src + (size_t)r * 1024, dst + r * 1040);
  }

  // per-lane epilogue constants (same cols for every M-tile)
  float bv[4], w3c[4][3];
#pragma unroll
  for (int ni = 0; ni < 4; ++ni) {
    const int n = Nbase + wc + ni * 16 + lm;
    bv[ni] = bc2[n];
    w3c[ni][0] = Wc3[n * 3 + 0];
    w3c[ni][1] = Wc3[n * 3 + 1];
    w3c[ni][2] = Wc3[n * 3 + 2];
  }

  __syncthreads();                                 // Bs ready (only barrier)

  // A base: this lane reads rows (.. + wr + mi*16 + lm), k-bytes kt*64 + q*16
  const char* Abase = (const char*)R + ((size_t)Mgrp * 2048 + wr + lm) * 1024 + q * 16;

#pragma unroll 1
  for (int mt = 0; mt < 8; ++mt) {
    const char* Am = Abase + (size_t)mt * 256 * 1024;
    v4f acc[4][4];
#pragma unroll
    for (int mi = 0; mi < 4; ++mi)
#pragma unroll
      for (int ni = 0; ni < 4; ++ni) acc[mi][ni] = (v4f){0.f, 0.f, 0.f, 0.f};

    v8s a_cur[4];
#pragma unroll
    for (int mi = 0; mi < 4; ++mi)
      a_cur[mi] = *(const v8s*)(Am + mi * 16384);

#pragma unroll 4
    for (int kt = 0; kt < 16; ++kt) {
      // prefetch A for kt+1 (clamped redundant load on the last iter)
      const int knx = (kt < 15) ? kt + 1 : 15;
      v8s a_nxt[4];
#pragma unroll
      for (int mi = 0; mi < 4; ++mi)
        a_nxt[mi] = *(const v8s*)(Am + mi * 16384 + knx * 64);
      v8s b4[4];
#pragma unroll
      for (int ni = 0; ni < 4; ++ni)
        b4[ni] = *(const v8s*)((const char*)Bs + (wc + ni * 16 + lm) * 1040 + kt * 64 + q * 16);
#pragma unroll
      for (int mi = 0; mi < 4; ++mi)
#pragma unroll
        for (int ni = 0; ni < 4; ++ni)
          acc[mi][ni] = __builtin_amdgcn_mfma_f32_16x16x32_bf16(a_cur[mi], b4[ni], acc[mi][ni], 0, 0, 0);
#pragma unroll
      for (int mi = 0; mi < 4; ++mi) a_cur[mi] = a_nxt[mi];
    }

    // epilogue: relu + bias, conv3 partials, DPP 16-lane reduce, atomic into fine
    const int m_base = Mgrp * 2048 + mt * 256 + wr;
#pragma unroll
    for (int mi = 0; mi < 4; ++mi) {
      float p[4][3];
#pragma unroll
      for (int r = 0; r < 4; ++r) { p[r][0] = 0.f; p[r][1] = 0.f; p[r][2] = 0.f; }
#pragma unroll
      for (int ni = 0; ni < 4; ++ni)
#pragma unroll
        for (int r = 0; r < 4; ++r) {
          const float v = fmaxf(acc[mi][ni][r] + bv[ni], 0.f);
          p[r][0] = fmaf(v, w3c[ni][0], p[r][0]);
          p[r][1] = fmaf(v, w3c[ni][1], p[r][1]);
          p[r][2] = fmaf(v, w3c[ni][2], p[r][2]);
        }
#pragma unroll
      for (int r = 0; r < 4; ++r)
#pragma unroll
        for (int j = 0; j < 3; ++j) {
          const float s = rsum16(p[r][j]);
          if (lm == 0)
            atomicAdd(&fine[(size_t)(m_base + mi * 16 + q * 4 + r) * 3 + j], s);
        }
    }
  }
}

extern "C" void kernel_launch(void* const* d_in, const int* in_sizes, int n_in,
                              void* d_out, int out_size, void* d_ws, size_t ws_size,
                              hipStream_t stream) {
  const float* fea = (const float*)d_in[0];
  const float* Wl1 = (const float*)d_in[1];
  const float* bl1 = (const float*)d_in[2];
  const float* Wl2 = (const float*)d_in[3];
  const float* bl2 = (const float*)d_in[4];
  const float* Wc1 = (const float*)d_in[5];
  const float* bc1 = (const float*)d_in[6];
  const float* Wc2 = (const float*)d_in[7];
  const float* bc2 = (const float*)d_in[8];
  const float* Wc3 = (const float*)d_in[9];
  const float* bc3 = (const float*)d_in[10];
  float* xout = (float*)d_out;                 // (8,1024,3)
  float* fine = (float*)d_out + 24576;         // (8,16384,3)
  char* ws = (char*)d_ws;
  float* h1  = (float*)ws;                     // 32 KB
  float* xf  = (float*)(ws + 32768);           // 96 KB
  float* gp  = (float*)(ws + 131072);          // 16 KB
  bf16*  W2T = (bf16*)(ws + 147456);           // 512 KB
  bf16*  R   = (bf16*)(ws + 1048576);          // 128 MB

  k_prep<<<1024, 256, 0, stream>>>(fea, Wl1, bl1, Wc1, bc1, Wc2, h1, gp, W2T);
  k_lin2<<<1536, 256, 0, stream>>>(h1, Wl2, bl2, bc3, xf, xout, fine);
  k_R<<<32768, 256, 0, stream>>>(gp, xf, Wc1, R);
  k_gemm<<<256, 512, 0, stream>>>(R, W2T, bc2, Wc3, fine);
}

// Round 6
// 372.274 us; speedup vs baseline: 1.2294x; 1.2294x over previous
//
#include <hip/hip_runtime.h>
#include <hip/hip_bf16.h>
#include <stdint.h>

typedef __hip_bfloat16 bf16;
typedef __attribute__((ext_vector_type(8))) short v8s;   // 8 bf16 in 4 VGPRs
typedef __attribute__((ext_vector_type(4))) float v4f;   // MFMA C/D frag

__device__ __forceinline__ bf16 tob(float x) { return __float2bfloat16(x); }

// async global->LDS, 16B/lane; canonical wave-uniform base + lane*16 pattern
__device__ __forceinline__ void gload16(const void* g, void* l) {
  __builtin_amdgcn_global_load_lds(
      (const __attribute__((address_space(1))) uint32_t*)g,
      (__attribute__((address_space(3))) uint32_t*)l, 16, 0, 0);
}

// sum over the 16 lanes of a DPP row (VALU pipe only); verified R4/R5
__device__ __forceinline__ float rsum16(float v) {
  union { float f; int i; } u, w;
  u.f = v;
  w.i = __builtin_amdgcn_update_dpp(u.i, u.i, 0x121, 0xf, 0xf, false); u.f += w.f;
  w.i = __builtin_amdgcn_update_dpp(u.i, u.i, 0x122, 0xf, 0xf, false); u.f += w.f;
  w.i = __builtin_amdgcn_update_dpp(u.i, u.i, 0x124, 0xf, 0xf, false); u.f += w.f;
  w.i = __builtin_amdgcn_update_dpp(u.i, u.i, 0x128, 0xf, 0xf, false); u.f += w.f;
  return u.f;
}

// ============ merged prep: [0,512) lin1, [512,768) gp, [768,1024) w2t ============
__global__ void k_prep(const float* __restrict__ fea, const float* __restrict__ Wl1,
                       const float* __restrict__ bl1, const float* __restrict__ Wc1,
                       const float* __restrict__ bc1, const float* __restrict__ Wc2,
                       float* __restrict__ h1, float* __restrict__ gp,
                       bf16* __restrict__ W2T) {
  const int blk = blockIdx.x;
  if (blk < 768) {                       // lin1 or gp: 16 outputs x 16 k-slices
    __shared__ float red[256];
    const int nl = threadIdx.x & 15, ks = threadIdx.x >> 4;
    const bool isl1 = blk < 512;
    const int o = (isl1 ? blk : blk - 512) * 16 + nl;
    const int b = isl1 ? (o >> 10) : (o >> 9);
    const int n = isl1 ? (o & 1023) : (o & 511);
    const int LD = isl1 ? 1024 : 512;
    const float* fr = fea + (b << 10) + ks * 64;
    const float* wp = (isl1 ? Wl1 : (Wc1 + (size_t)5 * 512)) + (size_t)(ks * 64) * LD + n;
    float a0 = 0.f, a1 = 0.f, a2 = 0.f, a3 = 0.f;
#pragma unroll 4
    for (int j = 0; j < 64; j += 4) {
      a0 = fmaf(fr[j + 0], wp[(size_t)(j + 0) * LD], a0);
      a1 = fmaf(fr[j + 1], wp[(size_t)(j + 1) * LD], a1);
      a2 = fmaf(fr[j + 2], wp[(size_t)(j + 2) * LD], a2);
      a3 = fmaf(fr[j + 3], wp[(size_t)(j + 3) * LD], a3);
    }
    red[threadIdx.x] = (a0 + a1) + (a2 + a3);
    __syncthreads();
    if (threadIdx.x < 16) {
      float s = isl1 ? bl1[n] : bc1[n];
#pragma unroll
      for (int i = 0; i < 16; ++i) s += red[i * 16 + threadIdx.x];
      if (isl1) h1[o] = fmaxf(s, 0.f); else gp[o] = s;
    }
  } else {                               // W2T[n,k] = bf16(Wc2[k,n])
    __shared__ float tile[32][33];
    const int id = blk - 768;
    const int bx = id & 15, by = id >> 4;
    const int c = threadIdx.x & 31, r8 = threadIdx.x >> 5;
#pragma unroll
    for (int i = 0; i < 4; ++i) {
      int r = r8 + i * 8;
      tile[r][c] = Wc2[(by * 32 + r) * 512 + bx * 32 + c];
    }
    __syncthreads();
#pragma unroll
    for (int i = 0; i < 4; ++i) {
      int r = r8 + i * 8;
      W2T[(size_t)(bx * 32 + r) * 512 + by * 32 + c] = tob(tile[c][r]);
    }
  }
}

// ============ x = h1 @ W_l2 + b_l2; writes xout and seeds fine = x + bc3 ============
__global__ void k_lin2(const float* __restrict__ h1, const float* __restrict__ W,
                       const float* __restrict__ bias, const float* __restrict__ bc3,
                       float* __restrict__ xf, float* __restrict__ xout,
                       float* __restrict__ fine) {
  __shared__ float red[256];
  const int nl = threadIdx.x & 15, ks = threadIdx.x >> 4;
  const int o = blockIdx.x * 16 + nl;            // 0..24575
  const int b = o / 3072, n = o - b * 3072;
  const float* hr = h1 + (b << 10) + ks * 64;
  const float* wp = W + (size_t)(ks * 64) * 3072 + n;
  float a0 = 0.f, a1 = 0.f, a2 = 0.f, a3 = 0.f;
#pragma unroll 4
  for (int j = 0; j < 64; j += 4) {
    a0 = fmaf(hr[j + 0], wp[(size_t)(j + 0) * 3072], a0);
    a1 = fmaf(hr[j + 1], wp[(size_t)(j + 1) * 3072], a1);
    a2 = fmaf(hr[j + 2], wp[(size_t)(j + 2) * 3072], a2);
    a3 = fmaf(hr[j + 3], wp[(size_t)(j + 3) * 3072], a3);
  }
  red[threadIdx.x] = (a0 + a1) + (a2 + a3);
  __syncthreads();
  if (threadIdx.x < 16) {
    float s = bias[n];
#pragma unroll
    for (int i = 0; i < 16; ++i) s += red[i * 16 + threadIdx.x];
    xf[o] = s;
    xout[o] = s;
    const int c = n / 3, j = n - c * 3;
    const float seed = s + bc3[j];
    float* fp = fine + ((size_t)b * 16384 + c * 16) * 3 + j;
#pragma unroll
    for (int g = 0; g < 16; ++g) fp[g * 3] = seed;
  }
}

// ============ R[m,k] = bf16(relu(gp + grid·W01 + x·W234))  (131072,512) ============
__global__ void k_R(const float* __restrict__ gp, const float* __restrict__ xf,
                    const float* __restrict__ Wc1, bf16* __restrict__ R) {
  const int idx = blockIdx.x * 256 + threadIdx.x;  // 8388608 threads, 8 k each
  const int m = idx >> 6;
  const int kb = (idx & 63) << 3;
  const int b = m >> 14, f = m & 16383, c = f >> 4, g = f & 15;
  const float gx = -0.05f + (float)(g & 3) * (0.1f / 3.0f);
  const float gy = -0.05f + (float)(g >> 2) * (0.1f / 3.0f);
  const float* xp = xf + (b * 1024 + c) * 3;
  const float x0 = xp[0], x1 = xp[1], x2 = xp[2];
  const float* gpr = gp + (b << 9) + kb;
  const float* w0 = Wc1 + 0 * 512 + kb;
  const float* w1 = Wc1 + 1 * 512 + kb;
  const float* w2 = Wc1 + 2 * 512 + kb;
  const float* w3 = Wc1 + 3 * 512 + kb;
  const float* w4 = Wc1 + 4 * 512 + kb;
  union { bf16 h[8]; uint4 u; } out;
#pragma unroll
  for (int i = 0; i < 8; ++i) {
    float v = gpr[i];
    v = fmaf(gx, w0[i], v);
    v = fmaf(gy, w1[i], v);
    v = fmaf(x0, w2[i], v);
    v = fmaf(x1, w3[i], v);
    v = fmaf(x2, w4[i], v);
    out.h[i] = tob(fmaxf(v, 0.f));
  }
  *(uint4*)(R + (size_t)m * 512 + kb) = out.u;
}

// ============ m97-structure GEMM: 128x128 tile, BK=32, 2-barrier K-loop ============
// 4096 blocks x 256 thr. XCD-swizzled so the 4 N-blocks of one M-tile share an
// XCD (A-slice L2-local). Coalesced gload16 staging for BOTH A and B (the R4/R5
// per-lane global A-feeds were the regression). Epilogue: conv3 partial over this
// block's 128 cols, DPP 16-lane reduce, atomicAdd into fine (pre-seeded x+bc3).
__global__ __launch_bounds__(256)
void k_gemm(const bf16* __restrict__ R, const bf16* __restrict__ W2T,
            const float* __restrict__ bc2, const float* __restrict__ Wc3,
            float* __restrict__ fine) {
  __shared__ __align__(16) bf16 As[128 * 32];
  __shared__ __align__(16) bf16 Bs[128 * 32];
  const int t = threadIdx.x;
  const int w = t >> 6, l = t & 63, q = l >> 4, lm = l & 15;
  const int wm = w >> 1, wn = w & 1;
  // XCD swizzle: xcd = blk&7; all 4 bn of a given bm land on the same xcd
  const int blk = blockIdx.x;
  const int bn = (blk >> 3) & 3;
  const int bm = (blk & 7) * 128 + (blk >> 5);
  const int m0 = bm * 128, n0 = bn * 128;

  const char* Ra = (const char*)R + (size_t)(m0 + (t >> 2)) * 1024 + (t & 3) * 16;
  const char* Rb = Ra + 64 * 1024;
  const char* Wa = (const char*)W2T + (size_t)(n0 + (t >> 2)) * 1024 + (t & 3) * 16;
  const char* Wb = Wa + 64 * 1024;
  char* Asb = (char*)As;
  char* Bsb = (char*)Bs;

  v4f acc[4][4];
#pragma unroll
  for (int mi = 0; mi < 4; ++mi)
#pragma unroll
    for (int ni = 0; ni < 4; ++ni) acc[mi][ni] = (v4f){0.f, 0.f, 0.f, 0.f};

  for (int kt = 0; kt < 16; ++kt) {
    const int kb = kt << 6;              // 32 bf16 = 64 B per row per step
    __syncthreads();
    gload16(Ra + kb, Asb + t * 16);
    gload16(Rb + kb, Asb + 4096 + t * 16);
    gload16(Wa + kb, Bsb + t * 16);
    gload16(Wb + kb, Bsb + 4096 + t * 16);
    __syncthreads();
    v8s af[4], bfr[4];
#pragma unroll
    for (int mi = 0; mi < 4; ++mi)
      af[mi] = *(const v8s*)(Asb + ((wm * 64 + mi * 16 + lm) << 6) + (q << 4));
#pragma unroll
    for (int ni = 0; ni < 4; ++ni)
      bfr[ni] = *(const v8s*)(Bsb + ((wn * 64 + ni * 16 + lm) << 6) + (q << 4));
#pragma unroll
    for (int mi = 0; mi < 4; ++mi)
#pragma unroll
      for (int ni = 0; ni < 4; ++ni)
        acc[mi][ni] = __builtin_amdgcn_mfma_f32_16x16x32_bf16(af[mi], bfr[ni], acc[mi][ni], 0, 0, 0);
  }

  // epilogue: h2 = relu(acc + bc2); conv3 partials over this block's cols;
  // DPP 16-lane reduce; atomicAdd into fine (4 bn-blocks + 2 wn-waves per row)
#pragma unroll
  for (int mi = 0; mi < 4; ++mi) {
    float p[4][3];
#pragma unroll
    for (int r = 0; r < 4; ++r) { p[r][0] = 0.f; p[r][1] = 0.f; p[r][2] = 0.f; }
#pragma unroll
    for (int ni = 0; ni < 4; ++ni) {
      const int n = n0 + wn * 64 + ni * 16 + lm;
      const float bv = bc2[n];
      const float w30 = Wc3[n * 3 + 0];
      const float w31 = Wc3[n * 3 + 1];
      const float w32 = Wc3[n * 3 + 2];
#pragma unroll
      for (int r = 0; r < 4; ++r) {
        const float v = fmaxf(acc[mi][ni][r] + bv, 0.f);
        p[r][0] = fmaf(v, w30, p[r][0]);
        p[r][1] = fmaf(v, w31, p[r][1]);
        p[r][2] = fmaf(v, w32, p[r][2]);
      }
    }
#pragma unroll
    for (int r = 0; r < 4; ++r)
#pragma unroll
      for (int j = 0; j < 3; ++j) {
        const float s = rsum16(p[r][j]);
        if (lm == 0)
          atomicAdd(&fine[(size_t)(m0 + wm * 64 + mi * 16 + q * 4 + r) * 3 + j], s);
      }
  }
}

extern "C" void kernel_launch(void* const* d_in, const int* in_sizes, int n_in,
                              void* d_out, int out_size, void* d_ws, size_t ws_size,
                              hipStream_t stream) {
  const float* fea = (const float*)d_in[0];
  const float* Wl1 = (const float*)d_in[1];
  const float* bl1 = (const float*)d_in[2];
  const float* Wl2 = (const float*)d_in[3];
  const float* bl2 = (const float*)d_in[4];
  const float* Wc1 = (const float*)d_in[5];
  const float* bc1 = (const float*)d_in[6];
  const float* Wc2 = (const float*)d_in[7];
  const float* bc2 = (const float*)d_in[8];
  const float* Wc3 = (const float*)d_in[9];
  const float* bc3 = (const float*)d_in[10];
  float* xout = (float*)d_out;                 // (8,1024,3)
  float* fine = (float*)d_out + 24576;         // (8,16384,3)
  char* ws = (char*)d_ws;
  float* h1  = (float*)ws;                     // 32 KB
  float* xf  = (float*)(ws + 32768);           // 96 KB
  float* gp  = (float*)(ws + 131072);          // 16 KB
  bf16*  W2T = (bf16*)(ws + 147456);           // 512 KB
  bf16*  R   = (bf16*)(ws + 1048576);          // 128 MB

  k_prep<<<1024, 256, 0, stream>>>(fea, Wl1, bl1, Wc1, bc1, Wc2, h1, gp, W2T);
  k_lin2<<<1536, 256, 0, stream>>>(h1, Wl2, bl2, bc3, xf, xout, fine);
  k_R<<<32768, 256, 0, stream>>>(gp, xf, Wc1, R);
  k_gemm<<<4096, 256, 0, stream>>>(R, W2T, bc2, Wc3, fine);
}